// Round 9
// baseline (228.678 us; speedup 1.0000x reference)
//
#include <hip/hip_runtime.h>

typedef __attribute__((ext_vector_type(8))) __bf16 bf16x8;
typedef __attribute__((ext_vector_type(4))) __bf16 bf16x4;
typedef __attribute__((ext_vector_type(4))) float f32x4;

static constexpr int S = 2048;
static constexpr int D = 1024;
static constexpr int BATCH = 2;
static constexpr int M_ROWS = BATCH * S;  // 4096

#define GLOAD_LDS16(gp, lp)                                                        \
  __builtin_amdgcn_global_load_lds((const __attribute__((address_space(1))) void*)(gp), \
                                   (__attribute__((address_space(3))) void*)(lp), 16, 0, 0)

// ---------------- f32 -> bf16 casts ----------------
__global__ __launch_bounds__(256) void cast_f32_bf16(const float* __restrict__ in,
                                                     __bf16* __restrict__ out) {
  int i = (blockIdx.x * 256 + threadIdx.x) * 4;
  *reinterpret_cast<bf16x4*>(out + i) =
      __builtin_convertvector(*reinterpret_cast<const f32x4*>(in + i), bf16x4);
}

__global__ __launch_bounds__(256) void cast_w4(const float* __restrict__ w0, const float* __restrict__ w1,
                                               const float* __restrict__ w2, const float* __restrict__ w3,
                                               __bf16* __restrict__ o0, __bf16* __restrict__ o1,
                                               __bf16* __restrict__ o2, __bf16* __restrict__ o3) {
  const float* in = blockIdx.y == 0 ? w0 : blockIdx.y == 1 ? w1 : blockIdx.y == 2 ? w2 : w3;
  __bf16* out = blockIdx.y == 0 ? o0 : blockIdx.y == 1 ? o1 : blockIdx.y == 2 ? o2 : o3;
  int i = (blockIdx.x * 256 + threadIdx.x) * 4;
  *reinterpret_cast<bf16x4*>(out + i) =
      __builtin_convertvector(*reinterpret_cast<const f32x4*>(in + i), bf16x4);
}

// ---------------- GEMM core: C[m0:+128, n0:+128] = A[M,K] @ Bm[N,K]^T ----------------
template <typename OutT>
__device__ __forceinline__ void gemm_core(const __bf16* __restrict__ A,
                                          const __bf16* __restrict__ Bm,
                                          OutT* __restrict__ C, int m0, int n0, int K, int ldc,
                                          __bf16* At, __bf16* Bt) {
  const int tid = threadIdx.x;
  const int w = tid >> 6, l = tid & 63;
  const int wr = w >> 1, wc = w & 1;
  const int ln = l & 15, gr = l >> 4;

  const int srow = w * 32 + (l >> 2);
  const int scol = (l & 3) * 8;
  const size_t aoff = (size_t)(m0 + srow) * K + scol;
  const size_t boff = (size_t)(n0 + srow) * K + scol;
  __bf16* lA = At + w * 2 * 512;
  __bf16* lB = Bt + w * 2 * 512;

  f32x4 acc[4][4] = {};

  for (int k0 = 0; k0 < K; k0 += 32) {
    __syncthreads();
    GLOAD_LDS16(A + aoff + k0, lA);
    GLOAD_LDS16(A + aoff + (size_t)16 * K + k0, lA + 512);
    GLOAD_LDS16(Bm + boff + k0, lB);
    GLOAD_LDS16(Bm + boff + (size_t)16 * K + k0, lB + 512);
    __syncthreads();

    bf16x8 af[4], bfr[4];
#pragma unroll
    for (int mi = 0; mi < 4; mi++)
      af[mi] = *reinterpret_cast<const bf16x8*>(&At[(wr * 64 + mi * 16 + ln) * 32 + gr * 8]);
#pragma unroll
    for (int ni = 0; ni < 4; ni++)
      bfr[ni] = *reinterpret_cast<const bf16x8*>(&Bt[(wc * 64 + ni * 16 + ln) * 32 + gr * 8]);
#pragma unroll
    for (int mi = 0; mi < 4; mi++)
#pragma unroll
      for (int ni = 0; ni < 4; ni++)
        acc[mi][ni] = __builtin_amdgcn_mfma_f32_16x16x32_bf16(af[mi], bfr[ni], acc[mi][ni], 0, 0, 0);
  }

#pragma unroll
  for (int mi = 0; mi < 4; mi++)
#pragma unroll
    for (int ni = 0; ni < 4; ni++)
#pragma unroll
      for (int r = 0; r < 4; r++) {
        int row = m0 + wr * 64 + mi * 16 + gr * 4 + r;
        int col = n0 + wc * 64 + ni * 16 + ln;
        float v = acc[mi][ni][r];
        if constexpr (__is_same(OutT, float))
          C[(size_t)row * ldc + col] = v;
        else
          C[(size_t)row * ldc + col] = (__bf16)v;
      }
}

// Fused QKV projection (768 blocks): Q = X Wq^T, K = X Wk^T, V^T = Wv X^T.
__global__ __launch_bounds__(256) void qkv_gemm(const __bf16* __restrict__ xb,
                                                const __bf16* __restrict__ wq,
                                                const __bf16* __restrict__ wk,
                                                const __bf16* __restrict__ wv,
                                                __bf16* __restrict__ q, __bf16* __restrict__ k,
                                                __bf16* __restrict__ vt) {
  __shared__ __bf16 At[128 * 32];
  __shared__ __bf16 Bt[128 * 32];
  const int id = blockIdx.x;
  const __bf16 *A, *B;
  __bf16* C;
  int m0, n0, ldc;
  if (id < 512) {  // Q or K: C[4096,1024] = xb @ W^T
    A = xb;
    B = (id < 256) ? wq : wk;
    C = (id < 256) ? q : k;
    int t = id & 255;
    m0 = (t >> 3) * 128;
    n0 = (t & 7) * 128;
    ldc = 1024;
  } else {  // V^T: C[1024,4096] = wv @ xb^T
    int t = id - 512;
    A = wv;
    B = xb;
    C = vt;
    m0 = (t & 7) * 128;
    n0 = (t >> 3) * 128;
    ldc = 4096;
  }
  gemm_core<__bf16>(A, B, C, m0, n0, 1024, ldc, At, Bt);
}

__global__ __launch_bounds__(256) void wo_gemm(const __bf16* __restrict__ ob,
                                               const __bf16* __restrict__ wo,
                                               float* __restrict__ out) {
  __shared__ __bf16 At[128 * 32];
  __shared__ __bf16 Bt[128 * 32];
  gemm_core<float>(ob, wo, out, blockIdx.y * 128, blockIdx.x * 128, 1024, 1024, At, Bt);
}

// ---------------- causal flash attention ----------------
// 512 blocks x 512 threads = 2 blocks/CU, 16 waves/CU, 4 waves/SIMD.
// Wave = one 16-row q-tile (4096 tiles total), 32-key iterations.
// SIMD-balanced: waves w and w+4 get paired tiles qt and 127-qt (65 iters/pair);
// every block an identical 260-iteration workload. XCD-pinned (4 heads/XCD).
// Software pipeline per wave: QK^T(t+1) issues before softmax(t).
// Swapped-operand MFMAs; defer-max (THR=8, log2 domain); exp2 softmax.
__global__ __launch_bounds__(512, 4) void attn_kernel(const __bf16* __restrict__ Qb,
                                                      const __bf16* __restrict__ Kb,
                                                      const __bf16* __restrict__ VTb,
                                                      __bf16* __restrict__ Ob) {
  __shared__ __bf16 pt_all[8][16][40];  // per-wave P tile [q][key], stride 40

  const int lin = blockIdx.x;        // 0..511
  const int xcd = lin & 7;
  const int idx = lin >> 3;          // 0..63
  const int bh = xcd * 4 + (idx >> 4);  // 4 heads per XCD
  const int j = idx & 15;            // 0..15
  const int b = bh >> 4, h = bh & 15;

  const int tid = threadIdx.x;
  const int w = tid >> 6, l = tid & 63;
  const int ln = l & 15, gr = l >> 4;

  // SIMD-balanced tile assignment: w<4 -> qt=4j+w (0..63); w>=4 -> 127-(4j+w-4)
  const int qt = (w < 4) ? (j * 4 + w) : (131 - j * 4 - w);
  const int q0 = qt * 16;
  const int n = (qt >> 1) + 1;            // number of 32-key tiles
  const int moff = q0 - 32 * (n - 1);     // tail-mask offset: 0 (qt even) or 16 (qt odd)

  const __bf16* Qp = Qb + (size_t)b * S * D + h * 64;
  const __bf16* Kp = Kb + (size_t)b * S * D + h * 64;
  const __bf16* Vt = VTb + (size_t)(h * 64) * M_ROWS + b * S;
  __bf16 (*pt)[40] = pt_all[w];

  const float SCALE2 = 0.125f * 1.44269504f;  // 1/sqrt(64) * log2(e)
  const float NEG = -1e30f;

  bf16x8 qf[2];
#pragma unroll
  for (int s = 0; s < 2; s++)
    qf[s] = *reinterpret_cast<const bf16x8*>(
        Qp + (size_t)(q0 + ln) * D + s * 32 + gr * 8);

  f32x4 oacc[4] = {};
  float mr = NEG, ls = 0.f;

  auto loadK = [&](bf16x8 (&dst)[2][2], int kk) {
#pragma unroll
    for (int c = 0; c < 2; c++)
#pragma unroll
      for (int s = 0; s < 2; s++)
        dst[c][s] = *reinterpret_cast<const bf16x8*>(
            Kp + (size_t)(kk + c * 16 + ln) * D + s * 32 + gr * 8);
  };
  auto loadV = [&](bf16x8 (&dst)[4], int kk) {
#pragma unroll
    for (int t = 0; t < 4; t++)
      dst[t] = *reinterpret_cast<const bf16x8*>(
          Vt + (size_t)(t * 16 + ln) * M_ROWS + kk + gr * 8);
  };
  auto qk = [&](f32x4 (&st)[2], bf16x8 (&kf)[2][2]) {
    __builtin_amdgcn_s_setprio(1);
#pragma unroll
    for (int c = 0; c < 2; c++) {
      f32x4 z = {};
      z = __builtin_amdgcn_mfma_f32_16x16x32_bf16(kf[c][0], qf[0], z, 0, 0, 0);
      z = __builtin_amdgcn_mfma_f32_16x16x32_bf16(kf[c][1], qf[1], z, 0, 0, 0);
      st[c] = z;
    }
    __builtin_amdgcn_s_setprio(0);
  };
  // softmax(t) + PV(t). st layout: lane holds S[q=ln][key=16c+4gr+r].
  auto smpv = [&](f32x4 (&st)[2], bf16x8 (&vf)[4], int t) {
    const bool tail = (t == n - 1);
    float pv[8];
    float tm = NEG;
#pragma unroll
    for (int c = 0; c < 2; c++)
#pragma unroll
      for (int r = 0; r < 4; r++) {
        float v = st[c][r] * SCALE2;
        if (tail) v = (c * 16 + 4 * gr + r <= moff + ln) ? v : NEG;
        pv[c * 4 + r] = v;
        tm = fmaxf(tm, v);
      }
    tm = fmaxf(tm, __shfl_xor(tm, 16));
    tm = fmaxf(tm, __shfl_xor(tm, 32));
    // defer-max: rescale only when some row's max grew by > 8 (log2 domain)
    if (!__all(tm - mr <= 8.0f)) {
      float nm = fmaxf(mr, tm);
      float a = __builtin_exp2f(mr - nm);
      mr = nm;
      ls *= a;
#pragma unroll
      for (int tt = 0; tt < 4; tt++)
#pragma unroll
        for (int r = 0; r < 4; r++) oacc[tt][r] *= a;
    }
    float ps = 0.f;
#pragma unroll
    for (int i = 0; i < 8; i++) {
      pv[i] = __builtin_exp2f(pv[i] - mr);
      ps += pv[i];
    }
    ps += __shfl_xor(ps, 16);
    ps += __shfl_xor(ps, 32);
    ls += ps;
#pragma unroll
    for (int c = 0; c < 2; c++) {
      bf16x4 pk = {(__bf16)pv[c * 4 + 0], (__bf16)pv[c * 4 + 1],
                   (__bf16)pv[c * 4 + 2], (__bf16)pv[c * 4 + 3]};
      *reinterpret_cast<bf16x4*>(&pt[ln][c * 16 + 4 * gr]) = pk;
    }
    bf16x8 pp = *reinterpret_cast<const bf16x8*>(&pt[ln][gr * 8]);
    __builtin_amdgcn_s_setprio(1);
#pragma unroll
    for (int tt = 0; tt < 4; tt++)
      oacc[tt] = __builtin_amdgcn_mfma_f32_16x16x32_bf16(vf[tt], pp, oacc[tt], 0, 0, 0);
    __builtin_amdgcn_s_setprio(0);
  };

  // ---- pipelined main loop (manual 2-unroll, static register sets) ----
  f32x4 stA[2], stB[2];
  bf16x8 kf0[2][2], kf1[2][2], vf0[4], vf1[4];

  loadK(kf0, 0);
  loadV(vf0, 0);
  if (n > 1) {
    loadK(kf1, 32);
    loadV(vf1, 32);
  }
  qk(stA, kf0);  // st(0)

  auto iter_step = [&](f32x4 (&stCur)[2], f32x4 (&stNxt)[2],
                       bf16x8 (&kfNxt)[2][2], bf16x8 (&kfTgt)[2][2],
                       bf16x8 (&vfCur)[4], int t) {
    if (t + 1 < n) qk(stNxt, kfNxt);            // MFMA for t+1 overlaps softmax(t)
    if (t + 2 < n) loadK(kfTgt, 32 * (t + 2));  // K(t) slot dead; full-iter prefetch
    smpv(stCur, vfCur, t);
    if (t + 2 < n) loadV(vfCur, 32 * (t + 2));  // V(t) consumed; ~2-iter prefetch
  };

  int t = 0;
  for (;;) {
    iter_step(stA, stB, kf1, kf0, vf0, t);  // even t
    if (++t >= n) break;
    iter_step(stB, stA, kf0, kf1, vf1, t);  // odd t
    if (++t >= n) break;
  }

  // ---- normalize + store (lane holds O[q=ln][d=tt*16+4gr+r]) ----
  {
    float inv = 1.0f / ls;
    size_t row = (size_t)(b * S + q0 + ln);
#pragma unroll
    for (int tt = 0; tt < 4; tt++) {
      bf16x4 ov = {(__bf16)(oacc[tt][0] * inv), (__bf16)(oacc[tt][1] * inv),
                   (__bf16)(oacc[tt][2] * inv), (__bf16)(oacc[tt][3] * inv)};
      *reinterpret_cast<bf16x4*>(Ob + row * D + h * 64 + tt * 16 + gr * 4) = ov;
    }
  }
}

// ---------------- launcher ----------------
extern "C" void kernel_launch(void* const* d_in, const int* in_sizes, int n_in,
                              void* d_out, int out_size, void* d_ws, size_t ws_size,
                              hipStream_t stream) {
  const float* x = (const float*)d_in[0];
  const float* Wq = (const float*)d_in[1];
  const float* Wk = (const float*)d_in[2];
  const float* Wv = (const float*)d_in[3];
  const float* Wo = (const float*)d_in[4];
  float* out = (float*)d_out;

  char* ws = (char*)d_ws;
  const size_t MB = 1024 * 1024;
  __bf16* xb = (__bf16*)(ws + 0 * MB);
  __bf16* qb = (__bf16*)(ws + 8 * MB);
  __bf16* kb = (__bf16*)(ws + 16 * MB);
  __bf16* vtb = (__bf16*)(ws + 24 * MB);  // V^T [1024][4096]
  __bf16* ob = (__bf16*)(ws + 32 * MB);
  __bf16* wqb = (__bf16*)(ws + 40 * MB);
  __bf16* wkb = (__bf16*)(ws + 42 * MB);
  __bf16* wvb = (__bf16*)(ws + 44 * MB);
  __bf16* wob = (__bf16*)(ws + 46 * MB);

  const int nx = M_ROWS * D;  // 4,194,304
  const int nw = D * D;       // 1,048,576

  cast_f32_bf16<<<nx / 4 / 256, 256, 0, stream>>>(x, xb);
  cast_w4<<<dim3(nw / 4 / 256, 4), 256, 0, stream>>>(Wq, Wk, Wv, Wo, wqb, wkb, wvb, wob);

  qkv_gemm<<<768, 256, 0, stream>>>(xb, wqb, wkb, wvb, qb, kb, vtb);

  attn_kernel<<<512, 512, 0, stream>>>(qb, kb, vtb, ob);

  wo_gemm<<<dim3(8, 32), 256, 0, stream>>>(ob, wob, out);
}

// Round 10
// 147.701 us; speedup vs baseline: 1.5483x; 1.5483x over previous
//
#include <hip/hip_runtime.h>

typedef __attribute__((ext_vector_type(8))) __bf16 bf16x8;
typedef __attribute__((ext_vector_type(4))) __bf16 bf16x4;
typedef __attribute__((ext_vector_type(2))) __bf16 bf16x2;
typedef __attribute__((ext_vector_type(4))) float f32x4;
typedef __attribute__((ext_vector_type(16))) float f32x16;
typedef __attribute__((ext_vector_type(4))) unsigned uint4v;

static constexpr int S = 2048;
static constexpr int D = 1024;
static constexpr int BATCH = 2;
static constexpr int M_ROWS = BATCH * S;  // 4096

#define GLOAD_LDS16(gp, lp)                                                        \
  __builtin_amdgcn_global_load_lds((const __attribute__((address_space(1))) void*)(gp), \
                                   (__attribute__((address_space(3))) void*)(lp), 16, 0, 0)

// ---------------- f32 -> bf16 casts ----------------
__global__ __launch_bounds__(256) void cast_f32_bf16(const float* __restrict__ in,
                                                     __bf16* __restrict__ out) {
  int i = (blockIdx.x * 256 + threadIdx.x) * 4;
  *reinterpret_cast<bf16x4*>(out + i) =
      __builtin_convertvector(*reinterpret_cast<const f32x4*>(in + i), bf16x4);
}

__global__ __launch_bounds__(256) void cast_w4(const float* __restrict__ w0, const float* __restrict__ w1,
                                               const float* __restrict__ w2, const float* __restrict__ w3,
                                               __bf16* __restrict__ o0, __bf16* __restrict__ o1,
                                               __bf16* __restrict__ o2, __bf16* __restrict__ o3) {
  const float* in = blockIdx.y == 0 ? w0 : blockIdx.y == 1 ? w1 : blockIdx.y == 2 ? w2 : w3;
  __bf16* out = blockIdx.y == 0 ? o0 : blockIdx.y == 1 ? o1 : blockIdx.y == 2 ? o2 : o3;
  int i = (blockIdx.x * 256 + threadIdx.x) * 4;
  *reinterpret_cast<bf16x4*>(out + i) =
      __builtin_convertvector(*reinterpret_cast<const f32x4*>(in + i), bf16x4);
}

// ---------------- GEMM core: C[m0:+128, n0:+128] = A[M,K] @ Bm[N,K]^T ----------------
template <typename OutT>
__device__ __forceinline__ void gemm_core(const __bf16* __restrict__ A,
                                          const __bf16* __restrict__ Bm,
                                          OutT* __restrict__ C, int m0, int n0, int K, int ldc,
                                          __bf16* At, __bf16* Bt) {
  const int tid = threadIdx.x;
  const int w = tid >> 6, l = tid & 63;
  const int wr = w >> 1, wc = w & 1;
  const int ln = l & 15, gr = l >> 4;

  const int srow = w * 32 + (l >> 2);
  const int scol = (l & 3) * 8;
  const size_t aoff = (size_t)(m0 + srow) * K + scol;
  const size_t boff = (size_t)(n0 + srow) * K + scol;
  __bf16* lA = At + w * 2 * 512;
  __bf16* lB = Bt + w * 2 * 512;

  f32x4 acc[4][4] = {};

  for (int k0 = 0; k0 < K; k0 += 32) {
    __syncthreads();
    GLOAD_LDS16(A + aoff + k0, lA);
    GLOAD_LDS16(A + aoff + (size_t)16 * K + k0, lA + 512);
    GLOAD_LDS16(Bm + boff + k0, lB);
    GLOAD_LDS16(Bm + boff + (size_t)16 * K + k0, lB + 512);
    __syncthreads();

    bf16x8 af[4], bfr[4];
#pragma unroll
    for (int mi = 0; mi < 4; mi++)
      af[mi] = *reinterpret_cast<const bf16x8*>(&At[(wr * 64 + mi * 16 + ln) * 32 + gr * 8]);
#pragma unroll
    for (int ni = 0; ni < 4; ni++)
      bfr[ni] = *reinterpret_cast<const bf16x8*>(&Bt[(wc * 64 + ni * 16 + ln) * 32 + gr * 8]);
#pragma unroll
    for (int mi = 0; mi < 4; mi++)
#pragma unroll
      for (int ni = 0; ni < 4; ni++)
        acc[mi][ni] = __builtin_amdgcn_mfma_f32_16x16x32_bf16(af[mi], bfr[ni], acc[mi][ni], 0, 0, 0);
  }

#pragma unroll
  for (int mi = 0; mi < 4; mi++)
#pragma unroll
    for (int ni = 0; ni < 4; ni++)
#pragma unroll
      for (int r = 0; r < 4; r++) {
        int row = m0 + wr * 64 + mi * 16 + gr * 4 + r;
        int col = n0 + wc * 64 + ni * 16 + ln;
        float v = acc[mi][ni][r];
        if constexpr (__is_same(OutT, float))
          C[(size_t)row * ldc + col] = v;
        else
          C[(size_t)row * ldc + col] = (__bf16)v;
      }
}

// Fused QKV projection (768 blocks): Q = X Wq^T, K = X Wk^T, V^T = Wv X^T.
__global__ __launch_bounds__(256) void qkv_gemm(const __bf16* __restrict__ xb,
                                                const __bf16* __restrict__ wq,
                                                const __bf16* __restrict__ wk,
                                                const __bf16* __restrict__ wv,
                                                __bf16* __restrict__ q, __bf16* __restrict__ k,
                                                __bf16* __restrict__ vt) {
  __shared__ __bf16 At[128 * 32];
  __shared__ __bf16 Bt[128 * 32];
  const int id = blockIdx.x;
  const __bf16 *A, *B;
  __bf16* C;
  int m0, n0, ldc;
  if (id < 512) {  // Q or K: C[4096,1024] = xb @ W^T
    A = xb;
    B = (id < 256) ? wq : wk;
    C = (id < 256) ? q : k;
    int t = id & 255;
    m0 = (t >> 3) * 128;
    n0 = (t & 7) * 128;
    ldc = 1024;
  } else {  // V^T: C[1024,4096] = wv @ xb^T
    int t = id - 512;
    A = wv;
    B = xb;
    C = vt;
    m0 = (t & 7) * 128;
    n0 = (t >> 3) * 128;
    ldc = 4096;
  }
  gemm_core<__bf16>(A, B, C, m0, n0, 1024, ldc, At, Bt);
}

__global__ __launch_bounds__(256) void wo_gemm(const __bf16* __restrict__ ob,
                                               const __bf16* __restrict__ wo,
                                               float* __restrict__ out) {
  __shared__ __bf16 At[128 * 32];
  __shared__ __bf16 Bt[128 * 32];
  gemm_core<float>(ob, wo, out, blockIdx.y * 128, blockIdx.x * 128, 1024, 1024, At, Bt);
}

// ---------------- causal flash attention ----------------
// r8 schedule (256 blocks x 8 waves, 1 block/CU, paired long+short tiles, XCD-pinned)
// with a 32x32-MFMA in-register engine (zero LDS):
//   S^T[key][q] = mfma_32x32x16(K, Q^T): q = lane&31 lane-local, 16 keys in regs
//   softmax: in-lane tree over 16 + ONE shfl_xor(32) (partner holds other 16 keys)
//   P^T PV B-fragment built in-register: pack bf16 pairs + 4 shfl_xor(32) + cndmask
//   O^T = mfma_32x32x16(V^T, P^T) -> packed 8B stores
// defer-max (THR=8 log2-domain), exp2 softmax, QK(t+1)-before-softmax(t) pipeline.
__global__ __launch_bounds__(512, 2) void attn_kernel(const __bf16* __restrict__ Qb,
                                                      const __bf16* __restrict__ Kb,
                                                      const __bf16* __restrict__ VTb,
                                                      __bf16* __restrict__ Ob) {
  const int lin = blockIdx.x;                      // 0..255
  const int wid = ((lin & 7) << 5) | (lin >> 3);   // XCD k owns wid in [32k, 32k+32)
  const int bh = wid >> 3;                         // 4 heads per XCD
  const int j = wid & 7;
  const int b = bh >> 4, h = bh & 15;

  const int tid = threadIdx.x;
  const int w = tid >> 6, l = tid & 63;
  const int q31 = l & 31, hi = l >> 5;

  // per-SIMD balanced tile assignment: (w, w+4) pairs sum to 65 iterations
  int qt;
  switch (w) {
    case 0: qt = j; break;
    case 1: qt = 16 + j; break;
    case 2: qt = 15 - j; break;
    case 3: qt = 31 - j; break;
    case 4: qt = 63 - j; break;
    case 5: qt = 47 - j; break;
    case 6: qt = 48 + j; break;
    default: qt = 32 + j; break;
  }
  const int q0 = qt * 32;
  const int n = qt + 1;  // number of 32-key tiles

  const __bf16* Qp = Qb + (size_t)b * S * D + h * 64;
  const __bf16* Kp = Kb + (size_t)b * S * D + h * 64;
  const __bf16* Vt = VTb + (size_t)(h * 64) * M_ROWS + b * S;

  const float SCALE2 = 0.125f * 1.44269504f;  // 1/sqrt(64) * log2(e)
  const float NEG = -1e30f;
  const float THR_RAW = 8.0f / SCALE2;  // defer-max threshold in raw-score domain

  // Q B-fragment: lane holds Q[q0+q31][ds*16 + hi*8 + j], ds=0..3
  bf16x8 qf[4];
#pragma unroll
  for (int ds = 0; ds < 4; ds++)
    qf[ds] = *reinterpret_cast<const bf16x8*>(
        Qp + (size_t)(q0 + q31) * D + ds * 16 + hi * 8);

  f32x16 oacc[2] = {};
  float mr = NEG, ls = 0.f;

  // K A-fragment: lane holds K[k0+q31][ds*16 + hi*8 + j]
  auto loadK = [&](bf16x8 (&dst)[4], int kk) {
#pragma unroll
    for (int ds = 0; ds < 4; ds++)
      dst[ds] = *reinterpret_cast<const bf16x8*>(
          Kp + (size_t)(kk + q31) * D + ds * 16 + hi * 8);
  };
  // V^T A-fragment: lane holds V^T[d0*32+q31][k0 + ks*16 + hi*8 + j]
  auto loadV = [&](bf16x8 (&dst)[2][2], int kk) {
#pragma unroll
    for (int d0 = 0; d0 < 2; d0++)
#pragma unroll
      for (int ks = 0; ks < 2; ks++)
        dst[d0][ks] = *reinterpret_cast<const bf16x8*>(
            Vt + (size_t)(d0 * 32 + q31) * M_ROWS + kk + ks * 16 + hi * 8);
  };
  auto qk = [&](f32x16& st, bf16x8 (&kf)[4]) {
    f32x16 z = {};
    __builtin_amdgcn_s_setprio(1);
#pragma unroll
    for (int ds = 0; ds < 4; ds++)
      z = __builtin_amdgcn_mfma_f32_32x32x16_bf16(kf[ds], qf[ds], z, 0, 0, 0);
    __builtin_amdgcn_s_setprio(0);
    st = z;
  };

  auto pack2 = [](float x, float y) -> unsigned {
    bf16x2 p;
    p[0] = (__bf16)x;
    p[1] = (__bf16)y;
    return __builtin_bit_cast(unsigned, p);
  };

  // softmax(t) + PV(t). st reg r holds S^T[key = (r&3)+8*(r>>2)+4*hi][q = q0+q31].
  auto smpv = [&](f32x16& st, bf16x8 (&vf)[2][2], int t) {
    const bool tail = (t == n - 1);
    float pv[16];
#pragma unroll
    for (int r = 0; r < 16; r++) {
      float v = st[r];
      if (tail) {
        int keyidx = (r & 3) + 8 * (r >> 2) + 4 * hi;
        v = (keyidx <= q31) ? v : NEG;
      }
      pv[r] = v;
    }
    // max tree over 16 + cross-half combine
    float t8[8], t4[4];
#pragma unroll
    for (int i = 0; i < 8; i++) t8[i] = fmaxf(pv[i], pv[i + 8]);
#pragma unroll
    for (int i = 0; i < 4; i++) t4[i] = fmaxf(t8[i], t8[i + 4]);
    float tm = fmaxf(fmaxf(t4[0], t4[1]), fmaxf(t4[2], t4[3]));
    tm = fmaxf(tm, __shfl_xor(tm, 32));
    // defer-max: rescale only when some row's max grew past threshold
    if (!__all(tm - mr <= THR_RAW)) {
      float nm = fmaxf(mr, tm);
      float a = __builtin_exp2f((mr - nm) * SCALE2);
      mr = nm;
      ls *= a;
#pragma unroll
      for (int d0 = 0; d0 < 2; d0++)
#pragma unroll
        for (int r = 0; r < 16; r++) oacc[d0][r] *= a;
    }
    const float mrs = mr * SCALE2;
#pragma unroll
    for (int r = 0; r < 16; r++)
      pv[r] = __builtin_exp2f(__builtin_fmaf(pv[r], SCALE2, -mrs));
    // sum tree + cross-half
    float s8[8], s4[4];
#pragma unroll
    for (int i = 0; i < 8; i++) s8[i] = pv[i] + pv[i + 8];
#pragma unroll
    for (int i = 0; i < 4; i++) s4[i] = s8[i] + s8[i + 4];
    float ps = (s4[0] + s4[1]) + (s4[2] + s4[3]);
    ps += __shfl_xor(ps, 32);
    ls += ps;

    // pack: blk b (regs 4b..4b+3, keys 8b+4hi..+3) -> dwords dw[2b], dw[2b+1]
    unsigned dw[8];
#pragma unroll
    for (int bb = 0; bb < 4; bb++) {
      dw[2 * bb] = pack2(pv[4 * bb], pv[4 * bb + 1]);
      dw[2 * bb + 1] = pack2(pv[4 * bb + 2], pv[4 * bb + 3]);
    }
    // build P^T B-fragments (8 consecutive keys/lane) via cross-half exchange
    __builtin_amdgcn_s_setprio(1);
#pragma unroll
    for (int ks = 0; ks < 2; ks++) {
      unsigned s0 = hi ? dw[4 * ks + 0] : dw[4 * ks + 2];
      unsigned s1 = hi ? dw[4 * ks + 1] : dw[4 * ks + 3];
      unsigned r0 = (unsigned)__shfl_xor((int)s0, 32);
      unsigned r1 = (unsigned)__shfl_xor((int)s1, 32);
      uint4v uv;
      uv.x = hi ? r0 : dw[4 * ks + 0];
      uv.y = hi ? r1 : dw[4 * ks + 1];
      uv.z = hi ? dw[4 * ks + 2] : r0;
      uv.w = hi ? dw[4 * ks + 3] : r1;
      bf16x8 pb = __builtin_bit_cast(bf16x8, uv);
      oacc[0] = __builtin_amdgcn_mfma_f32_32x32x16_bf16(vf[0][ks], pb, oacc[0], 0, 0, 0);
      oacc[1] = __builtin_amdgcn_mfma_f32_32x32x16_bf16(vf[1][ks], pb, oacc[1], 0, 0, 0);
    }
    __builtin_amdgcn_s_setprio(0);
  };

  // ---- pipelined main loop (manual 2-unroll, static register sets) ----
  f32x16 stA, stB;
  bf16x8 kf0[4], kf1[4], vf0[2][2], vf1[2][2];

  loadK(kf0, 0);
  loadV(vf0, 0);
  if (n > 1) {
    loadK(kf1, 32);
    loadV(vf1, 32);
  }
  qk(stA, kf0);  // st(0)

  auto iter_step = [&](f32x16& stCur, f32x16& stNxt, bf16x8 (&kfNxt)[4],
                       bf16x8 (&kfTgt)[4], bf16x8 (&vfCur)[2][2], int t) {
    if (t + 1 < n) qk(stNxt, kfNxt);            // MFMA for t+1 overlaps softmax(t)
    if (t + 2 < n) loadK(kfTgt, 32 * (t + 2));  // K(t) slot dead; full-iter prefetch
    smpv(stCur, vfCur, t);
    if (t + 2 < n) loadV(vfCur, 32 * (t + 2));  // V(t) consumed; ~2-iter prefetch
  };

  int t = 0;
  for (;;) {
    iter_step(stA, stB, kf1, kf0, vf0, t);  // even t
    if (++t >= n) break;
    iter_step(stB, stA, kf0, kf1, vf1, t);  // odd t
    if (++t >= n) break;
  }

  // ---- normalize + store (lane holds O^T[d = d0*32+8*blk+4*hi+rr][q = q0+q31]) ----
  {
    float inv = 1.0f / ls;
    size_t row = (size_t)(b * S + q0 + q31);
#pragma unroll
    for (int d0 = 0; d0 < 2; d0++)
#pragma unroll
      for (int bb = 0; bb < 4; bb++) {
        bf16x4 ov = {(__bf16)(oacc[d0][4 * bb + 0] * inv), (__bf16)(oacc[d0][4 * bb + 1] * inv),
                     (__bf16)(oacc[d0][4 * bb + 2] * inv), (__bf16)(oacc[d0][4 * bb + 3] * inv)};
        *reinterpret_cast<bf16x4*>(Ob + row * D + h * 64 + d0 * 32 + 8 * bb + 4 * hi) = ov;
      }
  }
}

// ---------------- launcher ----------------
extern "C" void kernel_launch(void* const* d_in, const int* in_sizes, int n_in,
                              void* d_out, int out_size, void* d_ws, size_t ws_size,
                              hipStream_t stream) {
  const float* x = (const float*)d_in[0];
  const float* Wq = (const float*)d_in[1];
  const float* Wk = (const float*)d_in[2];
  const float* Wv = (const float*)d_in[3];
  const float* Wo = (const float*)d_in[4];
  float* out = (float*)d_out;

  char* ws = (char*)d_ws;
  const size_t MB = 1024 * 1024;
  __bf16* xb = (__bf16*)(ws + 0 * MB);
  __bf16* qb = (__bf16*)(ws + 8 * MB);
  __bf16* kb = (__bf16*)(ws + 16 * MB);
  __bf16* vtb = (__bf16*)(ws + 24 * MB);  // V^T [1024][4096]
  __bf16* ob = (__bf16*)(ws + 32 * MB);
  __bf16* wqb = (__bf16*)(ws + 40 * MB);
  __bf16* wkb = (__bf16*)(ws + 42 * MB);
  __bf16* wvb = (__bf16*)(ws + 44 * MB);
  __bf16* wob = (__bf16*)(ws + 46 * MB);

  const int nx = M_ROWS * D;  // 4,194,304
  const int nw = D * D;       // 1,048,576

  cast_f32_bf16<<<nx / 4 / 256, 256, 0, stream>>>(x, xb);
  cast_w4<<<dim3(nw / 4 / 256, 4), 256, 0, stream>>>(Wq, Wk, Wv, Wo, wqb, wkb, wvb, wob);

  qkv_gemm<<<768, 256, 0, stream>>>(xb, wqb, wkb, wvb, qb, kb, vtb);

  attn_kernel<<<256, 512, 0, stream>>>(qb, kb, vtb, ob);

  wo_gemm<<<dim3(8, 32), 256, 0, stream>>>(ob, wob, out);
}